// Round 2
// baseline (153.012 us; speedup 1.0000x reference)
//
#include <hip/hip_runtime.h>
#include <math.h>

#define NB     8
#define NPTS   32768
#define KPRIM  128
#define NSKEL  2048
#define NCTRL  4
#define NT     16
#define NCURVE (KPRIM * NT)          // 2048 curve points per batch
#define TOTAL_OCC (NB * NPTS)        // 262144 rows (B*Np)

// workspace layout (in floats)
#define WS_ACC    0
#define WS_CURVES 16
#define WS_MINA   (WS_CURVES + NB * NCURVE * 4)
#define WS_MINB   (WS_MINA   + NB * NSKEL * 4)

// grid split for the fused main kernel
#define NBLK_OV   4096               // recon + overlap blocks (64 rows each)
#define NBLK_CHA  256                // chamfer A blocks
#define NBLK_CHB  256                // chamfer B blocks

// ---------------- curves: (B,K,T,3) = basis(16x4) @ (ctrl*w); also zero acc --
__global__ void curves_init_kernel(const float* __restrict__ prim,
                                   const float* __restrict__ w,
                                   const float* __restrict__ basis,
                                   float* __restrict__ curves,
                                   float* __restrict__ acc) {
    if (blockIdx.x == 0 && threadIdx.x < 16) acc[threadIdx.x] = 0.0f;
    int idx = blockIdx.x * blockDim.x + threadIdx.x;   // over NB*KPRIM*NT*4
    int d    = idx & 3;
    int rest = idx >> 2;          // b*K*T + ...
    int t    = rest % NT;
    int bk   = rest / NT;         // b*KPRIM + k
    float v = 0.0f;
    if (d < 3) {
        float ww = w[bk];
        const float* p  = prim + bk * 16;
        const float* bs = basis + t * NCTRL;
        v = ww * (bs[0] * p[0 * 3 + d] + bs[1] * p[1 * 3 + d] +
                  bs[2] * p[2 * 3 + d] + bs[3] * p[3 * 3 + d]);
    }
    int b = bk / KPRIM;
    int k = bk % KPRIM;
    curves[(size_t)(b * NCURVE + k * NT + t) * 4 + d] = v;
}

// ---------------- fused main: recon+overlap (HBM) and chamfer A/B (compute) --
__global__ void fused_main_kernel(const float4* __restrict__ pred4,
                                  const float4* __restrict__ gt4,
                                  const float4* __restrict__ occ4,
                                  const float* __restrict__ skel,
                                  const float4* __restrict__ curves,
                                  float* __restrict__ acc,
                                  float* __restrict__ minA,
                                  float* __restrict__ minB) {
    int bid = blockIdx.x;
    int t   = threadIdx.x;

    if (bid < NBLK_OV) {
        // ---- overlap: 64 rows (2048 contiguous float4) per block ----
        size_t base = (size_t)bid * 2048;
        float pen = 0.0f;
#pragma unroll
        for (int i = 0; i < 8; ++i) {
            float4 v = occ4[base + i * 256 + t];
            float s = (v.x > 0.5f ? v.x : 0.0f) + (v.y > 0.5f ? v.y : 0.0f) +
                      (v.z > 0.5f ? v.z : 0.0f) + (v.w > 0.5f ? v.w : 0.0f);
            s += __shfl_xor(s, 1);
            s += __shfl_xor(s, 2);
            s += __shfl_xor(s, 4);
            s += __shfl_xor(s, 8);
            s += __shfl_xor(s, 16);
            if ((t & 31) == 0) pen += fmaxf(s - 32.0f, 0.0f);
        }
        __shared__ float red[256];
        red[t] = pen; __syncthreads();
        for (int st = 128; st > 0; st >>= 1) {
            if (t < st) red[t] += red[t + st];
            __syncthreads();
        }
        if (t == 0) atomicAdd(&acc[1], red[0]);

        // ---- recon slice: 16 float4 per block, lanes 0..15 of wave 0 ----
        if (t < 16) {
            float4 p = pred4[bid * 16 + t];
            float4 g = gt4[bid * 16 + t];
            float dx = p.x - g.x, dy = p.y - g.y, dz = p.z - g.z, dw = p.w - g.w;
            float r = dx * dx + dy * dy + dz * dz + dw * dw;
            r += __shfl_xor(r, 1);
            r += __shfl_xor(r, 2);
            r += __shfl_xor(r, 4);
            r += __shfl_xor(r, 8);
            if (t == 0) atomicAdd(&acc[0], r);
        }
    } else if (bid < NBLK_OV + NBLK_CHA) {
        // ---- chamfer A: per skeleton point, min d2 over a 512-curve chunk --
        int bx = bid - NBLK_OV;        // b*32 + nb*4 + mc
        int b  = bx >> 5;
        int rm = bx & 31;
        int nb = rm >> 2;
        int mc = rm & 3;

        __shared__ float4 cp[512];
        const float4* csrc = curves + (size_t)b * NCURVE + mc * 512;
        cp[t]       = csrc[t];
        cp[t + 256] = csrc[t + 256];
        __syncthreads();

        int n = nb * 256 + t;
        const float* s = skel + ((size_t)b * NSKEL + n) * 3;
        float ax = s[0], ay = s[1], az = s[2];

        float m0 = 3.4e38f, m1 = 3.4e38f, m2 = 3.4e38f, m3 = 3.4e38f;
        for (int m = 0; m < 512; m += 4) {
            float4 c0 = cp[m], c1 = cp[m + 1], c2 = cp[m + 2], c3 = cp[m + 3];
            float dx, dy, dz;
            dx = ax - c0.x; dy = ay - c0.y; dz = az - c0.z;
            m0 = fminf(m0, fmaf(dz, dz, fmaf(dy, dy, dx * dx)));
            dx = ax - c1.x; dy = ay - c1.y; dz = az - c1.z;
            m1 = fminf(m1, fmaf(dz, dz, fmaf(dy, dy, dx * dx)));
            dx = ax - c2.x; dy = ay - c2.y; dz = az - c2.z;
            m2 = fminf(m2, fmaf(dz, dz, fmaf(dy, dy, dx * dx)));
            dx = ax - c3.x; dy = ay - c3.y; dz = az - c3.z;
            m3 = fminf(m3, fmaf(dz, dz, fmaf(dy, dy, dx * dx)));
        }
        float md = fminf(fminf(m0, m1), fminf(m2, m3));
        minA[((size_t)b * NSKEL + n) * 4 + mc] = md;
    } else {
        // ---- chamfer B: per curve point, min d2 over a 512-skeleton chunk --
        int bx = bid - NBLK_OV - NBLK_CHA;
        int b  = bx >> 5;
        int rm = bx & 31;
        int nb = rm >> 2;
        int mc = rm & 3;

        __shared__ float4 sp[512];
        float* sf = (float*)sp;
        const float* ssrc = skel + (size_t)b * NSKEL * 3 + (size_t)mc * 512 * 3;
        for (int i = t; i < 1536; i += 256) {
            int p = i / 3, c = i % 3;
            sf[p * 4 + c] = ssrc[i];
        }
        __syncthreads();

        int m = nb * 256 + t;
        float4 cpt = curves[(size_t)b * NCURVE + m];
        float ax = cpt.x, ay = cpt.y, az = cpt.z;

        float m0 = 3.4e38f, m1 = 3.4e38f, m2 = 3.4e38f, m3 = 3.4e38f;
        for (int n = 0; n < 512; n += 4) {
            float4 c0 = sp[n], c1 = sp[n + 1], c2 = sp[n + 2], c3 = sp[n + 3];
            float dx, dy, dz;
            dx = ax - c0.x; dy = ay - c0.y; dz = az - c0.z;
            m0 = fminf(m0, fmaf(dz, dz, fmaf(dy, dy, dx * dx)));
            dx = ax - c1.x; dy = ay - c1.y; dz = az - c1.z;
            m1 = fminf(m1, fmaf(dz, dz, fmaf(dy, dy, dx * dx)));
            dx = ax - c2.x; dy = ay - c2.y; dz = az - c2.z;
            m2 = fminf(m2, fmaf(dz, dz, fmaf(dy, dy, dx * dx)));
            dx = ax - c3.x; dy = ay - c3.y; dz = az - c3.z;
            m3 = fminf(m3, fmaf(dz, dz, fmaf(dy, dy, dx * dx)));
        }
        float md = fminf(fminf(m0, m1), fminf(m2, m3));
        minB[((size_t)b * NCURVE + m) * 4 + mc] = md;
    }
}

// ---------------- finalize: one block per batch ----------------
__device__ inline float blk_reduce(float v, float* red) {
    int t = threadIdx.x;
    __syncthreads();
    red[t] = v; __syncthreads();
    for (int st = 128; st > 0; st >>= 1) {
        if (t < st) red[t] += red[t + st];
        __syncthreads();
    }
    return red[0];
}

__global__ void finalize_kernel(const float* __restrict__ wts,
                                const float* __restrict__ acc,
                                const float* __restrict__ minA,
                                const float* __restrict__ minB,
                                float* __restrict__ out) {
    int b = blockIdx.x;
    int t = threadIdx.x;
    float ca = 0.0f, cb = 0.0f, ps = 0.0f;
    for (int i = t; i < NSKEL; i += 256) {
        const float* q = minA + ((size_t)b * NSKEL + i) * 4;
        ca += sqrtf(fminf(fminf(q[0], q[1]), fminf(q[2], q[3])));
    }
    for (int i = t; i < NCURVE; i += 256) {
        const float* q = minB + ((size_t)b * NCURVE + i) * 4;
        cb += sqrtf(fminf(fminf(q[0], q[1]), fminf(q[2], q[3])));
    }
    for (int i = t; i < NB * KPRIM; i += 256) {
        float x = wts[i];
        ps += 1.0f / (1.0f + expf(-x));
    }
    __shared__ float red[256];
    float ca_s = blk_reduce(ca, red);
    float cb_s = blk_reduce(cb, red);
    float ps_s = blk_reduce(ps, red);
    if (t == 0) {
        float recon = acc[0] / (float)TOTAL_OCC;
        float overl = 0.1f * acc[1] / (float)TOTAL_OCC;
        float pars  = 0.1f * sqrtf(ps_s);
        out[b] = recon + overl + pars + ca_s / (float)NSKEL + cb_s / (float)NCURVE;
    }
}

extern "C" void kernel_launch(void* const* d_in, const int* in_sizes, int n_in,
                              void* d_out, int out_size, void* d_ws, size_t ws_size,
                              hipStream_t stream) {
    const float* pred  = (const float*)d_in[0];
    const float* gt    = (const float*)d_in[1];
    const float* occ   = (const float*)d_in[2];
    const float* prim  = (const float*)d_in[3];
    const float* wts   = (const float*)d_in[4];
    const float* skel  = (const float*)d_in[5];
    const float* basis = (const float*)d_in[6];
    float* out = (float*)d_out;
    float* ws  = (float*)d_ws;

    float* acc    = ws + WS_ACC;
    float* curves = ws + WS_CURVES;
    float* minA   = ws + WS_MINA;
    float* minB   = ws + WS_MINB;

    curves_init_kernel<<<(NB * KPRIM * NT * 4) / 256, 256, 0, stream>>>(
        prim, wts, basis, curves, acc);
    fused_main_kernel<<<NBLK_OV + NBLK_CHA + NBLK_CHB, 256, 0, stream>>>(
        (const float4*)pred, (const float4*)gt, (const float4*)occ,
        skel, (const float4*)curves, acc, minA, minB);
    finalize_kernel<<<NB, 256, 0, stream>>>(wts, acc, minA, minB, out);
}

// Round 3
// 109.969 us; speedup vs baseline: 1.3914x; 1.3914x over previous
//
#include <hip/hip_runtime.h>
#include <math.h>

#define NB     8
#define NPTS   32768
#define KPRIM  128
#define NSKEL  2048
#define NCTRL  4
#define NT     16
#define NCURVE (KPRIM * NT)          // 2048 curve points per batch
#define TOTAL_OCC (NB * NPTS)        // 262144 rows (B*Np)

// workspace layout (in floats)
#define WS_ACC    0
#define WS_CURVES 16
#define WS_MINA   (WS_CURVES + NB * NCURVE * 4)
#define WS_MINB   (WS_MINA   + NB * NSKEL * 4)

// ---------------- curves: (B,K,T,3) = basis(16x4) @ (ctrl*w); also zero acc --
__global__ void curves_init_kernel(const float* __restrict__ prim,
                                   const float* __restrict__ w,
                                   const float* __restrict__ basis,
                                   float* __restrict__ curves,
                                   float* __restrict__ acc) {
    if (blockIdx.x == 0 && threadIdx.x < 16) acc[threadIdx.x] = 0.0f;
    int idx = blockIdx.x * blockDim.x + threadIdx.x;   // over NB*KPRIM*NT*4
    int d    = idx & 3;
    int rest = idx >> 2;          // b*K*T + ...
    int t    = rest % NT;
    int bk   = rest / NT;         // b*KPRIM + k
    float v = 0.0f;
    if (d < 3) {
        float ww = w[bk];
        const float* p  = prim + bk * 16;
        const float* bs = basis + t * NCTRL;
        v = ww * (bs[0] * p[0 * 3 + d] + bs[1] * p[1 * 3 + d] +
                  bs[2] * p[2 * 3 + d] + bs[3] * p[3 * 3 + d]);
    }
    int b = bk / KPRIM;
    int k = bk % KPRIM;
    curves[(size_t)(b * NCURVE + k * NT + t) * 4 + d] = v;
}

// ---------------- recon: mean((pred-gt)^2) ----------------
__global__ void recon_kernel(const float4* __restrict__ pred,
                             const float4* __restrict__ gt,
                             float* __restrict__ acc) {
    int idx = blockIdx.x * blockDim.x + threadIdx.x;   // over TOTAL_OCC/4
    float4 p = pred[idx];
    float4 g = gt[idx];
    float dx = p.x - g.x, dy = p.y - g.y, dz = p.z - g.z, dw = p.w - g.w;
    float s = dx * dx + dy * dy + dz * dz + dw * dw;

    __shared__ float red[256];
    int t = threadIdx.x;
    red[t] = s; __syncthreads();
    for (int st = 128; st > 0; st >>= 1) {
        if (t < st) red[t] += red[t + st];
        __syncthreads();
    }
    if (t == 0) atomicAdd(&acc[0], red[0]);
}

// ---------------- overlap: per-row masked sum, penalty ----------------
// block handles 64 rows (= 2048 float4 contiguous). 32-lane subgroup = 1 row.
__global__ void overlap_kernel(const float4* __restrict__ occ,
                               float* __restrict__ acc) {
    int t = threadIdx.x;
    size_t base = (size_t)blockIdx.x * 2048;
    float pen = 0.0f;
#pragma unroll
    for (int i = 0; i < 8; ++i) {
        int j = i * 256 + t;
        float4 v = occ[base + j];
        float s = (v.x > 0.5f ? v.x : 0.0f) + (v.y > 0.5f ? v.y : 0.0f) +
                  (v.z > 0.5f ? v.z : 0.0f) + (v.w > 0.5f ? v.w : 0.0f);
        // reduce across the 32 lanes that own this row
        s += __shfl_xor(s, 1);
        s += __shfl_xor(s, 2);
        s += __shfl_xor(s, 4);
        s += __shfl_xor(s, 8);
        s += __shfl_xor(s, 16);
        if ((t & 31) == 0) pen += fmaxf(s - 32.0f, 0.0f);
    }
    __shared__ float red[256];
    red[t] = pen; __syncthreads();
    for (int st = 128; st > 0; st >>= 1) {
        if (t < st) red[t] += red[t + st];
        __syncthreads();
    }
    if (t == 0) atomicAdd(&acc[1], red[0]);
}

// ---------------- chamfer A: per skeleton point, min d2 over curve chunk ----
__global__ void chamferA_kernel(const float* __restrict__ skel,
                                const float4* __restrict__ curves,
                                float* __restrict__ minA) {
    int bx = blockIdx.x;            // b*32 + nb*4 + mc
    int b  = bx >> 5;
    int rm = bx & 31;
    int nb = rm >> 2;
    int mc = rm & 3;

    __shared__ float4 cp[512];
    const float4* csrc = curves + (size_t)b * NCURVE + mc * 512;
    cp[threadIdx.x]       = csrc[threadIdx.x];
    cp[threadIdx.x + 256] = csrc[threadIdx.x + 256];
    __syncthreads();

    int n = nb * 256 + threadIdx.x;
    const float* s = skel + ((size_t)b * NSKEL + n) * 3;
    float ax = s[0], ay = s[1], az = s[2];

    float m0 = 3.4e38f, m1 = 3.4e38f, m2 = 3.4e38f, m3 = 3.4e38f;
    for (int m = 0; m < 512; m += 4) {
        float4 c0 = cp[m], c1 = cp[m + 1], c2 = cp[m + 2], c3 = cp[m + 3];
        float dx, dy, dz;
        dx = ax - c0.x; dy = ay - c0.y; dz = az - c0.z;
        m0 = fminf(m0, fmaf(dz, dz, fmaf(dy, dy, dx * dx)));
        dx = ax - c1.x; dy = ay - c1.y; dz = az - c1.z;
        m1 = fminf(m1, fmaf(dz, dz, fmaf(dy, dy, dx * dx)));
        dx = ax - c2.x; dy = ay - c2.y; dz = az - c2.z;
        m2 = fminf(m2, fmaf(dz, dz, fmaf(dy, dy, dx * dx)));
        dx = ax - c3.x; dy = ay - c3.y; dz = az - c3.z;
        m3 = fminf(m3, fmaf(dz, dz, fmaf(dy, dy, dx * dx)));
    }
    float md = fminf(fminf(m0, m1), fminf(m2, m3));
    minA[((size_t)b * NSKEL + n) * 4 + mc] = md;
}

// ---------------- chamfer B: per curve point, min d2 over skeleton chunk ----
__global__ void chamferB_kernel(const float* __restrict__ skel,
                                const float4* __restrict__ curves,
                                float* __restrict__ minB) {
    int bx = blockIdx.x;
    int b  = bx >> 5;
    int rm = bx & 31;
    int nb = rm >> 2;
    int mc = rm & 3;

    __shared__ float4 sp[512];
    float* sf = (float*)sp;
    const float* ssrc = skel + (size_t)b * NSKEL * 3 + (size_t)mc * 512 * 3;
    for (int i = threadIdx.x; i < 1536; i += 256) {
        int p = i / 3, c = i % 3;
        sf[p * 4 + c] = ssrc[i];
    }
    __syncthreads();

    int m = nb * 256 + threadIdx.x;
    float4 cpt = curves[(size_t)b * NCURVE + m];
    float ax = cpt.x, ay = cpt.y, az = cpt.z;

    float m0 = 3.4e38f, m1 = 3.4e38f, m2 = 3.4e38f, m3 = 3.4e38f;
    for (int n = 0; n < 512; n += 4) {
        float4 c0 = sp[n], c1 = sp[n + 1], c2 = sp[n + 2], c3 = sp[n + 3];
        float dx, dy, dz;
        dx = ax - c0.x; dy = ay - c0.y; dz = az - c0.z;
        m0 = fminf(m0, fmaf(dz, dz, fmaf(dy, dy, dx * dx)));
        dx = ax - c1.x; dy = ay - c1.y; dz = az - c1.z;
        m1 = fminf(m1, fmaf(dz, dz, fmaf(dy, dy, dx * dx)));
        dx = ax - c2.x; dy = ay - c2.y; dz = az - c2.z;
        m2 = fminf(m2, fmaf(dz, dz, fmaf(dy, dy, dx * dx)));
        dx = ax - c3.x; dy = ay - c3.y; dz = az - c3.z;
        m3 = fminf(m3, fmaf(dz, dz, fmaf(dy, dy, dx * dx)));
    }
    float md = fminf(fminf(m0, m1), fminf(m2, m3));
    minB[((size_t)b * NCURVE + m) * 4 + mc] = md;
}

// ---------------- finalize: one block per batch ----------------
__device__ inline float blk_reduce(float v, float* red) {
    int t = threadIdx.x;
    __syncthreads();
    red[t] = v; __syncthreads();
    for (int st = 128; st > 0; st >>= 1) {
        if (t < st) red[t] += red[t + st];
        __syncthreads();
    }
    return red[0];
}

__global__ void finalize_kernel(const float* __restrict__ wts,
                                const float* __restrict__ acc,
                                const float* __restrict__ minA,
                                const float* __restrict__ minB,
                                float* __restrict__ out) {
    int b = blockIdx.x;
    int t = threadIdx.x;
    float ca = 0.0f, cb = 0.0f, ps = 0.0f;
    for (int i = t; i < NSKEL; i += 256) {
        const float* q = minA + ((size_t)b * NSKEL + i) * 4;
        ca += sqrtf(fminf(fminf(q[0], q[1]), fminf(q[2], q[3])));
    }
    for (int i = t; i < NCURVE; i += 256) {
        const float* q = minB + ((size_t)b * NCURVE + i) * 4;
        cb += sqrtf(fminf(fminf(q[0], q[1]), fminf(q[2], q[3])));
    }
    for (int i = t; i < NB * KPRIM; i += 256) {
        float x = wts[i];
        ps += 1.0f / (1.0f + expf(-x));
    }
    __shared__ float red[256];
    float ca_s = blk_reduce(ca, red);
    float cb_s = blk_reduce(cb, red);
    float ps_s = blk_reduce(ps, red);
    if (t == 0) {
        float recon = acc[0] / (float)TOTAL_OCC;
        float overl = 0.1f * acc[1] / (float)TOTAL_OCC;
        float pars  = 0.1f * sqrtf(ps_s);
        out[b] = recon + overl + pars + ca_s / (float)NSKEL + cb_s / (float)NCURVE;
    }
}

extern "C" void kernel_launch(void* const* d_in, const int* in_sizes, int n_in,
                              void* d_out, int out_size, void* d_ws, size_t ws_size,
                              hipStream_t stream) {
    const float* pred  = (const float*)d_in[0];
    const float* gt    = (const float*)d_in[1];
    const float* occ   = (const float*)d_in[2];
    const float* prim  = (const float*)d_in[3];
    const float* wts   = (const float*)d_in[4];
    const float* skel  = (const float*)d_in[5];
    const float* basis = (const float*)d_in[6];
    float* out = (float*)d_out;
    float* ws  = (float*)d_ws;

    float* acc    = ws + WS_ACC;
    float* curves = ws + WS_CURVES;
    float* minA   = ws + WS_MINA;
    float* minB   = ws + WS_MINB;

    curves_init_kernel<<<(NB * KPRIM * NT * 4) / 256, 256, 0, stream>>>(
        prim, wts, basis, curves, acc);
    recon_kernel<<<(TOTAL_OCC / 4) / 256, 256, 0, stream>>>(
        (const float4*)pred, (const float4*)gt, acc);
    overlap_kernel<<<TOTAL_OCC / 64, 256, 0, stream>>>((const float4*)occ, acc);
    chamferA_kernel<<<NB * 8 * 4, 256, 0, stream>>>(skel, (const float4*)curves, minA);
    chamferB_kernel<<<NB * 8 * 4, 256, 0, stream>>>(skel, (const float4*)curves, minB);
    finalize_kernel<<<NB, 256, 0, stream>>>(wts, acc, minA, minB, out);
}

// Round 5
// 62.614 us; speedup vs baseline: 2.4437x; 1.7563x over previous
//
#include <hip/hip_runtime.h>
#include <math.h>

#define NB     8
#define NPTS   32768
#define KPRIM  128
#define NSKEL  2048
#define NCTRL  4
#define NT     16
#define NCURVE (KPRIM * NT)          // 2048 curve points per batch
#define TOTAL_OCC (NB * NPTS)        // 262144 rows (B*Np)

// workspace layout (in floats) — no atomics, all per-block partials
#define WS_CURVES 0
#define WS_MINA   (WS_CURVES + NB * NCURVE * 4)   // [b][n][8] chunk minima
#define WS_MINB   (WS_MINA   + NB * NSKEL * 8)    // [b][m][8]
#define WS_OVP    (WS_MINB   + NB * NCURVE * 8)   // overlap partials [4096]
#define WS_RCP    (WS_OVP + 4096)                 // recon partials [256]

#define NBLK_OV   4096
#define NBLK_RC   256

// ---------------- curves: (B,K,T,3) = basis(16x4) @ (ctrl*w) ----------------
__global__ void curves_kernel(const float* __restrict__ prim,
                              const float* __restrict__ w,
                              const float* __restrict__ basis,
                              float* __restrict__ curves) {
    int idx = blockIdx.x * blockDim.x + threadIdx.x;   // over NB*KPRIM*NT*4
    int d    = idx & 3;
    int rest = idx >> 2;
    int t    = rest % NT;
    int bk   = rest / NT;
    float v = 0.0f;
    if (d < 3) {
        float ww = w[bk];
        const float* p  = prim + bk * 16;
        const float* bs = basis + t * NCTRL;
        v = ww * (bs[0] * p[0 * 3 + d] + bs[1] * p[1 * 3 + d] +
                  bs[2] * p[2 * 3 + d] + bs[3] * p[3 * 3 + d]);
    }
    int b = bk / KPRIM;
    int k = bk % KPRIM;
    curves[(size_t)(b * NCURVE + k * NT + t) * 4 + d] = v;
}

// -------- stream kernel: overlap (blocks 0..4095) + recon (next 256) --------
__global__ void stream_kernel(const float4* __restrict__ occ,
                              const float4* __restrict__ pred,
                              const float4* __restrict__ gt,
                              float* __restrict__ ovp,
                              float* __restrict__ rcp) {
    int bid = blockIdx.x;
    int t   = threadIdx.x;
    __shared__ float sred[8];

    if (bid < NBLK_OV) {
        size_t base = (size_t)bid * 2048;
        // hoist all 8 loads for ILP (8 outstanding float4 loads per thread)
        float4 v0 = occ[base + 0 * 256 + t];
        float4 v1 = occ[base + 1 * 256 + t];
        float4 v2 = occ[base + 2 * 256 + t];
        float4 v3 = occ[base + 3 * 256 + t];
        float4 v4 = occ[base + 4 * 256 + t];
        float4 v5 = occ[base + 5 * 256 + t];
        float4 v6 = occ[base + 6 * 256 + t];
        float4 v7 = occ[base + 7 * 256 + t];
        float pen = 0.0f;
        float4 vv[8] = {v0, v1, v2, v3, v4, v5, v6, v7};
#pragma unroll
        for (int i = 0; i < 8; ++i) {
            float4 v = vv[i];
            float s = (v.x > 0.5f ? v.x : 0.0f) + (v.y > 0.5f ? v.y : 0.0f) +
                      (v.z > 0.5f ? v.z : 0.0f) + (v.w > 0.5f ? v.w : 0.0f);
            s += __shfl_xor(s, 1);
            s += __shfl_xor(s, 2);
            s += __shfl_xor(s, 4);
            s += __shfl_xor(s, 8);
            s += __shfl_xor(s, 16);
            if ((t & 31) == 0) pen += fmaxf(s - 32.0f, 0.0f);
        }
        if ((t & 31) == 0) sred[t >> 5] = pen;
        __syncthreads();
        if (t == 0) {
            float s = 0.0f;
#pragma unroll
            for (int j = 0; j < 8; ++j) s += sred[j];
            ovp[bid] = s;
        }
    } else {
        int bid2 = bid - NBLK_OV;
        int idx = bid2 * 256 + t;          // over TOTAL_OCC/4 = 65536
        float4 p = pred[idx];
        float4 g = gt[idx];
        float dx = p.x - g.x, dy = p.y - g.y, dz = p.z - g.z, dw = p.w - g.w;
        float s = dx * dx + dy * dy + dz * dz + dw * dw;
        s += __shfl_xor(s, 1);
        s += __shfl_xor(s, 2);
        s += __shfl_xor(s, 4);
        s += __shfl_xor(s, 8);
        s += __shfl_xor(s, 16);
        s += __shfl_xor(s, 32);
        if ((t & 63) == 0) sred[t >> 6] = s;
        __syncthreads();
        if (t == 0) rcp[bid2] = sred[0] + sred[1] + sred[2] + sred[3];
    }
}

// -------- chamfer: A (blocks 0..511) and B (blocks 512..1023) --------
// 8 chunks of 256 points -> 1024 blocks total, 2 blocks/CU, short loops.
__global__ void chamfer_kernel(const float* __restrict__ skel,
                               const float4* __restrict__ curves,
                               float* __restrict__ minA,
                               float* __restrict__ minB) {
    int bx = blockIdx.x;
    int t  = threadIdx.x;
    __shared__ float4 tile[256];

    if (bx < 512) {
        // A: per skeleton point, min over a 256-curve-point chunk
        int b  = bx >> 6;
        int rm = bx & 63;
        int nb = rm >> 3;      // skel chunk (8 x 256)
        int mc = rm & 7;       // curve chunk (8 x 256)
        tile[t] = curves[(size_t)b * NCURVE + mc * 256 + t];
        __syncthreads();

        int n = nb * 256 + t;
        const float* s = skel + ((size_t)b * NSKEL + n) * 3;
        float ax = s[0], ay = s[1], az = s[2];

        float m0 = 3.4e38f, m1 = 3.4e38f, m2 = 3.4e38f, m3 = 3.4e38f;
        for (int m = 0; m < 256; m += 4) {
            float4 c0 = tile[m], c1 = tile[m + 1], c2 = tile[m + 2], c3 = tile[m + 3];
            float dx, dy, dz;
            dx = ax - c0.x; dy = ay - c0.y; dz = az - c0.z;
            m0 = fminf(m0, fmaf(dz, dz, fmaf(dy, dy, dx * dx)));
            dx = ax - c1.x; dy = ay - c1.y; dz = az - c1.z;
            m1 = fminf(m1, fmaf(dz, dz, fmaf(dy, dy, dx * dx)));
            dx = ax - c2.x; dy = ay - c2.y; dz = az - c2.z;
            m2 = fminf(m2, fmaf(dz, dz, fmaf(dy, dy, dx * dx)));
            dx = ax - c3.x; dy = ay - c3.y; dz = az - c3.z;
            m3 = fminf(m3, fmaf(dz, dz, fmaf(dy, dy, dx * dx)));
        }
        float md = fminf(fminf(m0, m1), fminf(m2, m3));
        minA[((size_t)b * NSKEL + n) * 8 + mc] = md;
    } else {
        // B: per curve point, min over a 256-skeleton-point chunk
        int bx2 = bx - 512;
        int b  = bx2 >> 6;
        int rm = bx2 & 63;
        int mb = rm >> 3;      // curve-point chunk (8 x 256)
        int nc = rm & 7;       // skel chunk (8 x 256)
        float* sf = (float*)tile;
        const float* ssrc = skel + (size_t)b * NSKEL * 3 + (size_t)nc * 256 * 3;
        for (int i = t; i < 768; i += 256) {
            int p = i / 3, c = i % 3;
            sf[p * 4 + c] = ssrc[i];
        }
        __syncthreads();

        int m = mb * 256 + t;
        float4 cpt = curves[(size_t)b * NCURVE + m];
        float ax = cpt.x, ay = cpt.y, az = cpt.z;

        float m0 = 3.4e38f, m1 = 3.4e38f, m2 = 3.4e38f, m3 = 3.4e38f;
        for (int n = 0; n < 256; n += 4) {
            float4 c0 = tile[n], c1 = tile[n + 1], c2 = tile[n + 2], c3 = tile[n + 3];
            float dx, dy, dz;
            dx = ax - c0.x; dy = ay - c0.y; dz = az - c0.z;
            m0 = fminf(m0, fmaf(dz, dz, fmaf(dy, dy, dx * dx)));
            dx = ax - c1.x; dy = ay - c1.y; dz = az - c1.z;
            m1 = fminf(m1, fmaf(dz, dz, fmaf(dy, dy, dx * dx)));
            dx = ax - c2.x; dy = ay - c2.y; dz = az - c2.z;
            m2 = fminf(m2, fmaf(dz, dz, fmaf(dy, dy, dx * dx)));
            dx = ax - c3.x; dy = ay - c3.y; dz = az - c3.z;
            m3 = fminf(m3, fmaf(dz, dz, fmaf(dy, dy, dx * dx)));
        }
        float md = fminf(fminf(m0, m1), fminf(m2, m3));
        minB[((size_t)b * NCURVE + m) * 8 + nc] = md;
    }
}

// ---------------- finalize: one block per batch ----------------
__device__ inline float blk_reduce(float v, float* red) {
    int t = threadIdx.x;
    __syncthreads();
    red[t] = v; __syncthreads();
    for (int st = 128; st > 0; st >>= 1) {
        if (t < st) red[t] += red[t + st];
        __syncthreads();
    }
    return red[0];
}

__global__ void finalize_kernel(const float* __restrict__ wts,
                                const float* __restrict__ minA,
                                const float* __restrict__ minB,
                                const float* __restrict__ ovp,
                                const float* __restrict__ rcp,
                                float* __restrict__ out) {
    int b = blockIdx.x;
    int t = threadIdx.x;
    float ca = 0.0f, cb = 0.0f, ps = 0.0f, ov = 0.0f, rc = 0.0f;
    for (int i = t; i < NSKEL; i += 256) {
        const float* q = minA + ((size_t)b * NSKEL + i) * 8;
        float m = q[0];
#pragma unroll
        for (int j = 1; j < 8; ++j) m = fminf(m, q[j]);
        ca += sqrtf(m);
    }
    for (int i = t; i < NCURVE; i += 256) {
        const float* q = minB + ((size_t)b * NCURVE + i) * 8;
        float m = q[0];
#pragma unroll
        for (int j = 1; j < 8; ++j) m = fminf(m, q[j]);
        cb += sqrtf(m);
    }
    for (int i = t; i < NB * KPRIM; i += 256) {
        float x = wts[i];
        ps += 1.0f / (1.0f + expf(-x));
    }
    for (int i = t; i < NBLK_OV; i += 256) ov += ovp[i];
    rc = rcp[t];

    __shared__ float red[256];
    float ca_s = blk_reduce(ca, red);
    float cb_s = blk_reduce(cb, red);
    float ps_s = blk_reduce(ps, red);
    float ov_s = blk_reduce(ov, red);
    float rc_s = blk_reduce(rc, red);
    if (t == 0) {
        float recon = rc_s / (float)TOTAL_OCC;
        float overl = 0.1f * ov_s / (float)TOTAL_OCC;
        float pars  = 0.1f * sqrtf(ps_s);
        out[b] = recon + overl + pars + ca_s / (float)NSKEL + cb_s / (float)NCURVE;
    }
}

extern "C" void kernel_launch(void* const* d_in, const int* in_sizes, int n_in,
                              void* d_out, int out_size, void* d_ws, size_t ws_size,
                              hipStream_t stream) {
    const float* pred  = (const float*)d_in[0];
    const float* gt    = (const float*)d_in[1];
    const float* occ   = (const float*)d_in[2];
    const float* prim  = (const float*)d_in[3];
    const float* wts   = (const float*)d_in[4];
    const float* skel  = (const float*)d_in[5];
    const float* basis = (const float*)d_in[6];
    float* out = (float*)d_out;
    float* ws  = (float*)d_ws;

    float* curves = ws + WS_CURVES;
    float* minA   = ws + WS_MINA;
    float* minB   = ws + WS_MINB;
    float* ovp    = ws + WS_OVP;
    float* rcp    = ws + WS_RCP;

    curves_kernel<<<(NB * KPRIM * NT * 4) / 256, 256, 0, stream>>>(
        prim, wts, basis, curves);
    stream_kernel<<<NBLK_OV + NBLK_RC, 256, 0, stream>>>(
        (const float4*)occ, (const float4*)pred, (const float4*)gt, ovp, rcp);
    chamfer_kernel<<<1024, 256, 0, stream>>>(skel, (const float4*)curves, minA, minB);
    finalize_kernel<<<NB, 256, 0, stream>>>(wts, minA, minB, ovp, rcp, out);
}

// Round 7
// 48.843 us; speedup vs baseline: 3.1327x; 1.2819x over previous
//
#include <hip/hip_runtime.h>
#include <math.h>

#define NB     8
#define NPTS   32768
#define KPRIM  128
#define NSKEL  2048
#define NCTRL  4
#define NT     16
#define NCURVE (KPRIM * NT)          // 2048 curve points per batch
#define TOTAL_OCC (NB * NPTS)        // 262144 rows (B*Np)

// workspace layout (in floats) — no atomics, all per-block partials
#define WS_MINA   0                               // [b][n][8] chunk minima
#define WS_MINB   (WS_MINA + NB * NSKEL * 8)      // [b][m][8]
#define WS_OVP    (WS_MINB + NB * NCURVE * 8)     // overlap partials [4096]
#define WS_RCP    (WS_OVP + 4096)                 // recon partials [256]

// mega-kernel role ranges (compute first so it overlaps the streaming phase)
#define NBLK_CHA  512
#define NBLK_CHB  512
#define NBLK_RC   256
#define NBLK_OV   4096
#define RC_BASE   (NBLK_CHA + NBLK_CHB)           // 1024
#define OV_BASE   (RC_BASE + NBLK_RC)             // 1280
#define NBLK_ALL  (OV_BASE + NBLK_OV)             // 5376

// mega: chamferA | chamferB | recon | overlap, selected by blockIdx.x
__global__ void mega_kernel(const float4* __restrict__ occ,
                            const float4* __restrict__ pred,
                            const float4* __restrict__ gt,
                            const float* __restrict__ skel,
                            const float* __restrict__ prim,
                            const float* __restrict__ w,
                            const float* __restrict__ basis,
                            float* __restrict__ minA,
                            float* __restrict__ minB,
                            float* __restrict__ ovp,
                            float* __restrict__ rcp) {
    int bid = blockIdx.x;
    int t   = threadIdx.x;
    __shared__ float4 tile[256];
    float* sred = (float*)tile;

    if (bid < NBLK_CHA) {
        // ---- chamfer A: per skeleton point, min over 256 inline curve pts --
        int b  = bid >> 6;
        int rm = bid & 63;
        int nb = rm >> 3;      // skel chunk (8 x 256)
        int mc = rm & 7;       // curve chunk (8 x 256)
        {
            int k  = mc * 16 + (t >> 4);
            int tt = t & 15;
            int bk = b * KPRIM + k;
            float ww = w[bk];
            const float* p  = prim + bk * 16;
            const float* bs = basis + tt * 4;
            float x = ww * (bs[0] * p[0] + bs[1] * p[3] + bs[2] * p[6] + bs[3] * p[9]);
            float y = ww * (bs[0] * p[1] + bs[1] * p[4] + bs[2] * p[7] + bs[3] * p[10]);
            float z = ww * (bs[0] * p[2] + bs[1] * p[5] + bs[2] * p[8] + bs[3] * p[11]);
            tile[t] = make_float4(x, y, z, 0.0f);
        }
        __syncthreads();

        int n = nb * 256 + t;
        const float* s = skel + ((size_t)b * NSKEL + n) * 3;
        float ax = s[0], ay = s[1], az = s[2];

        float m0 = 3.4e38f, m1 = 3.4e38f, m2 = 3.4e38f, m3 = 3.4e38f;
        for (int m = 0; m < 256; m += 4) {
            float4 c0 = tile[m], c1 = tile[m + 1], c2 = tile[m + 2], c3 = tile[m + 3];
            float dx, dy, dz;
            dx = ax - c0.x; dy = ay - c0.y; dz = az - c0.z;
            m0 = fminf(m0, fmaf(dz, dz, fmaf(dy, dy, dx * dx)));
            dx = ax - c1.x; dy = ay - c1.y; dz = az - c1.z;
            m1 = fminf(m1, fmaf(dz, dz, fmaf(dy, dy, dx * dx)));
            dx = ax - c2.x; dy = ay - c2.y; dz = az - c2.z;
            m2 = fminf(m2, fmaf(dz, dz, fmaf(dy, dy, dx * dx)));
            dx = ax - c3.x; dy = ay - c3.y; dz = az - c3.z;
            m3 = fminf(m3, fmaf(dz, dz, fmaf(dy, dy, dx * dx)));
        }
        float md = fminf(fminf(m0, m1), fminf(m2, m3));
        minA[((size_t)b * NSKEL + n) * 8 + mc] = md;
    } else if (bid < NBLK_CHA + NBLK_CHB) {
        // ---- chamfer B: per inline curve point, min over 256 skel pts ----
        int bx2 = bid - NBLK_CHA;
        int b  = bx2 >> 6;
        int rm = bx2 & 63;
        int mb = rm >> 3;      // curve-point chunk (8 x 256)
        int nc = rm & 7;       // skel chunk (8 x 256)
        float* sf = (float*)tile;
        const float* ssrc = skel + (size_t)b * NSKEL * 3 + (size_t)nc * 256 * 3;
        for (int i = t; i < 768; i += 256) {
            int p = i / 3, c = i % 3;
            sf[p * 4 + c] = ssrc[i];
        }
        __syncthreads();

        int m  = mb * 256 + t;
        float ax, ay, az;
        {
            int k  = m >> 4;
            int tt = m & 15;
            int bk = b * KPRIM + k;
            float ww = w[bk];
            const float* p  = prim + bk * 16;
            const float* bs = basis + tt * 4;
            ax = ww * (bs[0] * p[0] + bs[1] * p[3] + bs[2] * p[6] + bs[3] * p[9]);
            ay = ww * (bs[0] * p[1] + bs[1] * p[4] + bs[2] * p[7] + bs[3] * p[10]);
            az = ww * (bs[0] * p[2] + bs[1] * p[5] + bs[2] * p[8] + bs[3] * p[11]);
        }

        float m0 = 3.4e38f, m1 = 3.4e38f, m2 = 3.4e38f, m3 = 3.4e38f;
        for (int n = 0; n < 256; n += 4) {
            float4 c0 = tile[n], c1 = tile[n + 1], c2 = tile[n + 2], c3 = tile[n + 3];
            float dx, dy, dz;
            dx = ax - c0.x; dy = ay - c0.y; dz = az - c0.z;
            m0 = fminf(m0, fmaf(dz, dz, fmaf(dy, dy, dx * dx)));
            dx = ax - c1.x; dy = ay - c1.y; dz = az - c1.z;
            m1 = fminf(m1, fmaf(dz, dz, fmaf(dy, dy, dx * dx)));
            dx = ax - c2.x; dy = ay - c2.y; dz = az - c2.z;
            m2 = fminf(m2, fmaf(dz, dz, fmaf(dy, dy, dx * dx)));
            dx = ax - c3.x; dy = ay - c3.y; dz = az - c3.z;
            m3 = fminf(m3, fmaf(dz, dz, fmaf(dy, dy, dx * dx)));
        }
        float md = fminf(fminf(m0, m1), fminf(m2, m3));
        minB[((size_t)b * NCURVE + m) * 8 + nc] = md;
    } else if (bid < OV_BASE) {
        // ---- recon: mean((pred-gt)^2) partials ----
        int bid2 = bid - RC_BASE;
        int idx = bid2 * 256 + t;          // over TOTAL_OCC/4 = 65536
        float4 p = pred[idx];
        float4 g = gt[idx];
        float dx = p.x - g.x, dy = p.y - g.y, dz = p.z - g.z, dw = p.w - g.w;
        float s = dx * dx + dy * dy + dz * dz + dw * dw;
        s += __shfl_xor(s, 1);
        s += __shfl_xor(s, 2);
        s += __shfl_xor(s, 4);
        s += __shfl_xor(s, 8);
        s += __shfl_xor(s, 16);
        s += __shfl_xor(s, 32);
        if ((t & 63) == 0) sred[t >> 6] = s;
        __syncthreads();
        if (t == 0) rcp[bid2] = sred[0] + sred[1] + sred[2] + sred[3];
    } else {
        // ---- overlap: 64 rows (2048 contiguous float4) per block ----
        int bid2 = bid - OV_BASE;
        size_t base = (size_t)bid2 * 2048;
        float4 v0 = occ[base + 0 * 256 + t];
        float4 v1 = occ[base + 1 * 256 + t];
        float4 v2 = occ[base + 2 * 256 + t];
        float4 v3 = occ[base + 3 * 256 + t];
        float4 v4 = occ[base + 4 * 256 + t];
        float4 v5 = occ[base + 5 * 256 + t];
        float4 v6 = occ[base + 6 * 256 + t];
        float4 v7 = occ[base + 7 * 256 + t];
        float pen = 0.0f;
        float4 vv[8] = {v0, v1, v2, v3, v4, v5, v6, v7};
#pragma unroll
        for (int i = 0; i < 8; ++i) {
            float4 v = vv[i];
            float s = (v.x > 0.5f ? v.x : 0.0f) + (v.y > 0.5f ? v.y : 0.0f) +
                      (v.z > 0.5f ? v.z : 0.0f) + (v.w > 0.5f ? v.w : 0.0f);
            s += __shfl_xor(s, 1);
            s += __shfl_xor(s, 2);
            s += __shfl_xor(s, 4);
            s += __shfl_xor(s, 8);
            s += __shfl_xor(s, 16);
            if ((t & 31) == 0) pen += fmaxf(s - 32.0f, 0.0f);
        }
        if ((t & 31) == 0) sred[t >> 5] = pen;
        __syncthreads();
        if (t == 0) {
            float s = 0.0f;
#pragma unroll
            for (int j = 0; j < 8; ++j) s += sred[j];
            ovp[bid2] = s;
        }
    }
}

// ---------------- finalize: one block per batch ----------------
__device__ inline float blk_reduce(float v, float* red) {
    int t = threadIdx.x;
    __syncthreads();
    red[t] = v; __syncthreads();
    for (int st = 128; st > 0; st >>= 1) {
        if (t < st) red[t] += red[t + st];
        __syncthreads();
    }
    return red[0];
}

__global__ void finalize_kernel(const float* __restrict__ wts,
                                const float* __restrict__ minA,
                                const float* __restrict__ minB,
                                const float* __restrict__ ovp,
                                const float* __restrict__ rcp,
                                float* __restrict__ out) {
    int b = blockIdx.x;
    int t = threadIdx.x;
    float ca = 0.0f, cb = 0.0f, ps = 0.0f, ov = 0.0f, rc = 0.0f;
    for (int i = t; i < NSKEL; i += 256) {
        const float* q = minA + ((size_t)b * NSKEL + i) * 8;
        float m = q[0];
#pragma unroll
        for (int j = 1; j < 8; ++j) m = fminf(m, q[j]);
        ca += sqrtf(m);
    }
    for (int i = t; i < NCURVE; i += 256) {
        const float* q = minB + ((size_t)b * NCURVE + i) * 8;
        float m = q[0];
#pragma unroll
        for (int j = 1; j < 8; ++j) m = fminf(m, q[j]);
        cb += sqrtf(m);
    }
    for (int i = t; i < NB * KPRIM; i += 256) {
        float x = wts[i];
        ps += 1.0f / (1.0f + expf(-x));
    }
    for (int i = t; i < NBLK_OV; i += 256) ov += ovp[i];
    rc = rcp[t];

    __shared__ float red[256];
    float ca_s = blk_reduce(ca, red);
    float cb_s = blk_reduce(cb, red);
    float ps_s = blk_reduce(ps, red);
    float ov_s = blk_reduce(ov, red);
    float rc_s = blk_reduce(rc, red);
    if (t == 0) {
        float recon = rc_s / (float)TOTAL_OCC;
        float overl = 0.1f * ov_s / (float)TOTAL_OCC;
        float pars  = 0.1f * sqrtf(ps_s);
        out[b] = recon + overl + pars + ca_s / (float)NSKEL + cb_s / (float)NCURVE;
    }
}

extern "C" void kernel_launch(void* const* d_in, const int* in_sizes, int n_in,
                              void* d_out, int out_size, void* d_ws, size_t ws_size,
                              hipStream_t stream) {
    const float* pred  = (const float*)d_in[0];
    const float* gt    = (const float*)d_in[1];
    const float* occ   = (const float*)d_in[2];
    const float* prim  = (const float*)d_in[3];
    const float* wts   = (const float*)d_in[4];
    const float* skel  = (const float*)d_in[5];
    const float* basis = (const float*)d_in[6];
    float* out = (float*)d_out;
    float* ws  = (float*)d_ws;

    float* minA = ws + WS_MINA;
    float* minB = ws + WS_MINB;
    float* ovp  = ws + WS_OVP;
    float* rcp  = ws + WS_RCP;

    mega_kernel<<<NBLK_ALL, 256, 0, stream>>>(
        (const float4*)occ, (const float4*)pred, (const float4*)gt,
        skel, prim, wts, basis, minA, minB, ovp, rcp);
    finalize_kernel<<<NB, 256, 0, stream>>>(wts, minA, minB, ovp, rcp, out);
}

// Round 8
// 44.298 us; speedup vs baseline: 3.4541x; 1.1026x over previous
//
#include <hip/hip_runtime.h>
#include <math.h>

#define NB     8
#define NPTS   32768
#define KPRIM  128
#define NSKEL  2048
#define NCTRL  4
#define NT     16
#define NCURVE (KPRIM * NT)          // 2048 curve points per batch
#define TOTAL_OCC (NB * NPTS)        // 262144 rows (B*Np)

// workspace layout (in floats) — no atomics, all per-block partials
#define WS_MINA   0                               // [b][n][8] chunk minima
#define WS_MINB   (WS_MINA + NB * NSKEL * 8)      // [b][m][8]
#define WS_OVP    (WS_MINB + NB * NCURVE * 8)     // overlap partials [4096]
#define WS_RCP    (WS_OVP + 4096)                 // recon partials [256]

// mega-kernel role ranges (compute first so it overlaps the streaming phase)
#define NBLK_CHA  512
#define NBLK_CHB  512
#define NBLK_RC   256
#define NBLK_OV   4096
#define RC_BASE   (NBLK_CHA + NBLK_CHB)           // 1024
#define OV_BASE   (RC_BASE + NBLK_RC)             // 1280
#define NBLK_ALL  (OV_BASE + NBLK_OV)             // 5376

// mega: chamferA | chamferB | recon | overlap, selected by blockIdx.x
__global__ void mega_kernel(const float4* __restrict__ occ,
                            const float4* __restrict__ pred,
                            const float4* __restrict__ gt,
                            const float* __restrict__ skel,
                            const float* __restrict__ prim,
                            const float* __restrict__ w,
                            const float* __restrict__ basis,
                            float* __restrict__ minA,
                            float* __restrict__ minB,
                            float* __restrict__ ovp,
                            float* __restrict__ rcp) {
    int bid = blockIdx.x;
    int t   = threadIdx.x;
    __shared__ float4 tile[256];
    float* sred = (float*)tile;

    if (bid < NBLK_CHA) {
        // ---- chamfer A: per skeleton point, min over 256 inline curve pts --
        int b  = bid >> 6;
        int rm = bid & 63;
        int nb = rm >> 3;      // skel chunk (8 x 256)
        int mc = rm & 7;       // curve chunk (8 x 256)
        {
            int k  = mc * 16 + (t >> 4);
            int tt = t & 15;
            int bk = b * KPRIM + k;
            float ww = w[bk];
            const float* p  = prim + bk * 16;
            const float* bs = basis + tt * 4;
            float x = ww * (bs[0] * p[0] + bs[1] * p[3] + bs[2] * p[6] + bs[3] * p[9]);
            float y = ww * (bs[0] * p[1] + bs[1] * p[4] + bs[2] * p[7] + bs[3] * p[10]);
            float z = ww * (bs[0] * p[2] + bs[1] * p[5] + bs[2] * p[8] + bs[3] * p[11]);
            tile[t] = make_float4(x, y, z, 0.0f);
        }
        __syncthreads();

        int n = nb * 256 + t;
        const float* s = skel + ((size_t)b * NSKEL + n) * 3;
        float ax = s[0], ay = s[1], az = s[2];

        float m0 = 3.4e38f, m1 = 3.4e38f, m2 = 3.4e38f, m3 = 3.4e38f;
        for (int m = 0; m < 256; m += 4) {
            float4 c0 = tile[m], c1 = tile[m + 1], c2 = tile[m + 2], c3 = tile[m + 3];
            float dx, dy, dz;
            dx = ax - c0.x; dy = ay - c0.y; dz = az - c0.z;
            m0 = fminf(m0, fmaf(dz, dz, fmaf(dy, dy, dx * dx)));
            dx = ax - c1.x; dy = ay - c1.y; dz = az - c1.z;
            m1 = fminf(m1, fmaf(dz, dz, fmaf(dy, dy, dx * dx)));
            dx = ax - c2.x; dy = ay - c2.y; dz = az - c2.z;
            m2 = fminf(m2, fmaf(dz, dz, fmaf(dy, dy, dx * dx)));
            dx = ax - c3.x; dy = ay - c3.y; dz = az - c3.z;
            m3 = fminf(m3, fmaf(dz, dz, fmaf(dy, dy, dx * dx)));
        }
        float md = fminf(fminf(m0, m1), fminf(m2, m3));
        minA[((size_t)b * NSKEL + n) * 8 + mc] = md;
    } else if (bid < NBLK_CHA + NBLK_CHB) {
        // ---- chamfer B: per inline curve point, min over 256 skel pts ----
        int bx2 = bid - NBLK_CHA;
        int b  = bx2 >> 6;
        int rm = bx2 & 63;
        int mb = rm >> 3;      // curve-point chunk (8 x 256)
        int nc = rm & 7;       // skel chunk (8 x 256)
        float* sf = (float*)tile;
        const float* ssrc = skel + (size_t)b * NSKEL * 3 + (size_t)nc * 256 * 3;
        for (int i = t; i < 768; i += 256) {
            int p = i / 3, c = i % 3;
            sf[p * 4 + c] = ssrc[i];
        }
        __syncthreads();

        int m  = mb * 256 + t;
        float ax, ay, az;
        {
            int k  = m >> 4;
            int tt = m & 15;
            int bk = b * KPRIM + k;
            float ww = w[bk];
            const float* p  = prim + bk * 16;
            const float* bs = basis + tt * 4;
            ax = ww * (bs[0] * p[0] + bs[1] * p[3] + bs[2] * p[6] + bs[3] * p[9]);
            ay = ww * (bs[0] * p[1] + bs[1] * p[4] + bs[2] * p[7] + bs[3] * p[10]);
            az = ww * (bs[0] * p[2] + bs[1] * p[5] + bs[2] * p[8] + bs[3] * p[11]);
        }

        float m0 = 3.4e38f, m1 = 3.4e38f, m2 = 3.4e38f, m3 = 3.4e38f;
        for (int n = 0; n < 256; n += 4) {
            float4 c0 = tile[n], c1 = tile[n + 1], c2 = tile[n + 2], c3 = tile[n + 3];
            float dx, dy, dz;
            dx = ax - c0.x; dy = ay - c0.y; dz = az - c0.z;
            m0 = fminf(m0, fmaf(dz, dz, fmaf(dy, dy, dx * dx)));
            dx = ax - c1.x; dy = ay - c1.y; dz = az - c1.z;
            m1 = fminf(m1, fmaf(dz, dz, fmaf(dy, dy, dx * dx)));
            dx = ax - c2.x; dy = ay - c2.y; dz = az - c2.z;
            m2 = fminf(m2, fmaf(dz, dz, fmaf(dy, dy, dx * dx)));
            dx = ax - c3.x; dy = ay - c3.y; dz = az - c3.z;
            m3 = fminf(m3, fmaf(dz, dz, fmaf(dy, dy, dx * dx)));
        }
        float md = fminf(fminf(m0, m1), fminf(m2, m3));
        minB[((size_t)b * NCURVE + m) * 8 + nc] = md;
    } else if (bid < OV_BASE) {
        // ---- recon: mean((pred-gt)^2) partials ----
        int bid2 = bid - RC_BASE;
        int idx = bid2 * 256 + t;          // over TOTAL_OCC/4 = 65536
        float4 p = pred[idx];
        float4 g = gt[idx];
        float dx = p.x - g.x, dy = p.y - g.y, dz = p.z - g.z, dw = p.w - g.w;
        float s = dx * dx + dy * dy + dz * dz + dw * dw;
        s += __shfl_xor(s, 1);
        s += __shfl_xor(s, 2);
        s += __shfl_xor(s, 4);
        s += __shfl_xor(s, 8);
        s += __shfl_xor(s, 16);
        s += __shfl_xor(s, 32);
        if ((t & 63) == 0) sred[t >> 6] = s;
        __syncthreads();
        if (t == 0) rcp[bid2] = sred[0] + sred[1] + sred[2] + sred[3];
    } else {
        // ---- overlap: 64 rows (2048 contiguous float4) per block ----
        int bid2 = bid - OV_BASE;
        size_t base = (size_t)bid2 * 2048;
        float4 v0 = occ[base + 0 * 256 + t];
        float4 v1 = occ[base + 1 * 256 + t];
        float4 v2 = occ[base + 2 * 256 + t];
        float4 v3 = occ[base + 3 * 256 + t];
        float4 v4 = occ[base + 4 * 256 + t];
        float4 v5 = occ[base + 5 * 256 + t];
        float4 v6 = occ[base + 6 * 256 + t];
        float4 v7 = occ[base + 7 * 256 + t];
        float pen = 0.0f;
        float4 vv[8] = {v0, v1, v2, v3, v4, v5, v6, v7};
#pragma unroll
        for (int i = 0; i < 8; ++i) {
            float4 v = vv[i];
            float s = (v.x > 0.5f ? v.x : 0.0f) + (v.y > 0.5f ? v.y : 0.0f) +
                      (v.z > 0.5f ? v.z : 0.0f) + (v.w > 0.5f ? v.w : 0.0f);
            s += __shfl_xor(s, 1);
            s += __shfl_xor(s, 2);
            s += __shfl_xor(s, 4);
            s += __shfl_xor(s, 8);
            s += __shfl_xor(s, 16);
            if ((t & 31) == 0) pen += fmaxf(s - 32.0f, 0.0f);
        }
        if ((t & 31) == 0) sred[t >> 5] = pen;
        __syncthreads();
        if (t == 0) {
            float s = 0.0f;
#pragma unroll
            for (int j = 0; j < 8; ++j) s += sred[j];
            ovp[bid2] = s;
        }
    }
}

// ---------------- finalize: one block per batch, vectorized loads ----------
__device__ inline float blk_reduce(float v, float* red) {
    int t = threadIdx.x;
    __syncthreads();
    red[t] = v; __syncthreads();
    for (int st = 128; st > 0; st >>= 1) {
        if (t < st) red[t] += red[t + st];
        __syncthreads();
    }
    return red[0];
}

__device__ inline float min8(float4 u, float4 v) {
    return fminf(fminf(fminf(u.x, u.y), fminf(u.z, u.w)),
                 fminf(fminf(v.x, v.y), fminf(v.z, v.w)));
}

__global__ void finalize_kernel(const float* __restrict__ wts,
                                const float* __restrict__ minA,
                                const float* __restrict__ minB,
                                const float* __restrict__ ovp,
                                const float* __restrict__ rcp,
                                float* __restrict__ out) {
    int b = blockIdx.x;
    int t = threadIdx.x;
    float ca = 0.0f, cb = 0.0f, ps = 0.0f, ov = 0.0f, rc;

    const float4* qa = (const float4*)(minA + (size_t)b * NSKEL * 8);
#pragma unroll
    for (int i = t; i < NSKEL; i += 256)          // 8 independent iterations
        ca += sqrtf(min8(qa[2 * i], qa[2 * i + 1]));

    const float4* qb = (const float4*)(minB + (size_t)b * NCURVE * 8);
#pragma unroll
    for (int i = t; i < NCURVE; i += 256)         // 8 independent iterations
        cb += sqrtf(min8(qb[2 * i], qb[2 * i + 1]));

#pragma unroll
    for (int i = t; i < NB * KPRIM; i += 256) {   // 4 iterations
        float x = wts[i];
        ps += 1.0f / (1.0f + expf(-x));
    }

    const float4* ov4 = (const float4*)ovp;
#pragma unroll
    for (int i = t; i < NBLK_OV / 4; i += 256) {  // 4 iterations of float4
        float4 v = ov4[i];
        ov += v.x + v.y + v.z + v.w;
    }
    rc = rcp[t];

    __shared__ float red[256];
    float ca_s = blk_reduce(ca, red);
    float cb_s = blk_reduce(cb, red);
    float ps_s = blk_reduce(ps, red);
    float ov_s = blk_reduce(ov, red);
    float rc_s = blk_reduce(rc, red);
    if (t == 0) {
        float recon = rc_s / (float)TOTAL_OCC;
        float overl = 0.1f * ov_s / (float)TOTAL_OCC;
        float pars  = 0.1f * sqrtf(ps_s);
        out[b] = recon + overl + pars + ca_s / (float)NSKEL + cb_s / (float)NCURVE;
    }
}

extern "C" void kernel_launch(void* const* d_in, const int* in_sizes, int n_in,
                              void* d_out, int out_size, void* d_ws, size_t ws_size,
                              hipStream_t stream) {
    const float* pred  = (const float*)d_in[0];
    const float* gt    = (const float*)d_in[1];
    const float* occ   = (const float*)d_in[2];
    const float* prim  = (const float*)d_in[3];
    const float* wts   = (const float*)d_in[4];
    const float* skel  = (const float*)d_in[5];
    const float* basis = (const float*)d_in[6];
    float* out = (float*)d_out;
    float* ws  = (float*)d_ws;

    float* minA = ws + WS_MINA;
    float* minB = ws + WS_MINB;
    float* ovp  = ws + WS_OVP;
    float* rcp  = ws + WS_RCP;

    mega_kernel<<<NBLK_ALL, 256, 0, stream>>>(
        (const float4*)occ, (const float4*)pred, (const float4*)gt,
        skel, prim, wts, basis, minA, minB, ovp, rcp);
    finalize_kernel<<<NB, 256, 0, stream>>>(wts, minA, minB, ovp, rcp, out);
}